// Round 1
// baseline (13.194 us; speedup 1.0000x reference)
//
#include <hip/hip_runtime.h>

// CenterLoss: B=2048, C=16384, D=2048.
// reference only keeps distmat[b, labels[b]] => compute ||x_b - centers[l_b]||^2
// directly as x_sq + c_sq - 2*dot (same algebra as reference for numerics).

#define FEAT_DIM 2048
#define BATCH 2048

__global__ __launch_bounds__(256) void center_dist_kernel(
    const float* __restrict__ x,
    const int* __restrict__ labels,
    const float* __restrict__ centers,
    float* __restrict__ dist_ws) {
    const int b = blockIdx.x;
    const int lbl = labels[b];
    const float4* xr = reinterpret_cast<const float4*>(x + (size_t)b * FEAT_DIM);
    const float4* cr = reinterpret_cast<const float4*>(centers + (size_t)lbl * FEAT_DIM);

    float sx2 = 0.f, sc2 = 0.f, sxc = 0.f;
    const int nvec = FEAT_DIM / 4;  // 512 float4 per row
    for (int i = threadIdx.x; i < nvec; i += 256) {
        float4 xv = xr[i];
        float4 cv = cr[i];
        sx2 += xv.x * xv.x + xv.y * xv.y + xv.z * xv.z + xv.w * xv.w;
        sc2 += cv.x * cv.x + cv.y * cv.y + cv.z * cv.z + cv.w * cv.w;
        sxc += xv.x * cv.x + xv.y * cv.y + xv.z * cv.z + xv.w * cv.w;
    }

    // intra-wave reduce (wave = 64 lanes)
    #pragma unroll
    for (int off = 32; off > 0; off >>= 1) {
        sx2 += __shfl_down(sx2, off, 64);
        sc2 += __shfl_down(sc2, off, 64);
        sxc += __shfl_down(sxc, off, 64);
    }

    __shared__ float red[3][4];
    const int wave = threadIdx.x >> 6;
    const int lane = threadIdx.x & 63;
    if (lane == 0) {
        red[0][wave] = sx2;
        red[1][wave] = sc2;
        red[2][wave] = sxc;
    }
    __syncthreads();
    if (threadIdx.x == 0) {
        float tx2 = 0.f, tc2 = 0.f, txc = 0.f;
        #pragma unroll
        for (int w = 0; w < 4; ++w) {
            tx2 += red[0][w];
            tc2 += red[1][w];
            txc += red[2][w];
        }
        float d = tx2 + tc2 - 2.0f * txc;
        d = fminf(fmaxf(d, 1e-12f), 1e12f);  // clip like reference
        dist_ws[b] = d;
    }
}

__global__ __launch_bounds__(256) void mean_kernel(
    const float* __restrict__ dist_ws, float* __restrict__ out) {
    float s = 0.f;
    for (int i = threadIdx.x; i < BATCH; i += 256) s += dist_ws[i];
    #pragma unroll
    for (int off = 32; off > 0; off >>= 1) s += __shfl_down(s, off, 64);
    __shared__ float red[4];
    const int wave = threadIdx.x >> 6;
    const int lane = threadIdx.x & 63;
    if (lane == 0) red[wave] = s;
    __syncthreads();
    if (threadIdx.x == 0) {
        float t = 0.f;
        #pragma unroll
        for (int w = 0; w < 4; ++w) t += red[w];
        out[0] = t / (float)BATCH;
    }
}

extern "C" void kernel_launch(void* const* d_in, const int* in_sizes, int n_in,
                              void* d_out, int out_size, void* d_ws, size_t ws_size,
                              hipStream_t stream) {
    const float* x = (const float*)d_in[0];
    const int* labels = (const int*)d_in[1];
    const float* centers = (const float*)d_in[2];
    float* out = (float*)d_out;
    float* dist_ws = (float*)d_ws;  // BATCH floats

    center_dist_kernel<<<BATCH, 256, 0, stream>>>(x, labels, centers, dist_ws);
    mean_kernel<<<1, 256, 0, stream>>>(dist_ws, out);
}